// Round 18
// baseline (528.776 us; speedup 1.0000x reference)
//
#include <hip/hip_runtime.h>

typedef _Float16 f16;
typedef _Float16 f16x4 __attribute__((ext_vector_type(4)));
typedef _Float16 f16x8 __attribute__((ext_vector_type(8)));
typedef float f32x4 __attribute__((ext_vector_type(4)));

#define MFMA32(A, B, C) __builtin_amdgcn_mfma_f32_16x16x32_f16((A), (B), (C), 0, 0, 0)
#if __has_builtin(__builtin_amdgcn_mfma_f32_16x16x16_f16)
#define MFMA16(A, B, C) __builtin_amdgcn_mfma_f32_16x16x16_f16((A), (B), (C), 0, 0, 0)
#else
#define MFMA16(A, B, C) __builtin_amdgcn_mfma_f32_16x16x16f16((A), (B), (C), 0, 0, 0)
#endif

// ---------------- prep: deinterleave weights to f16, bias tables ----------------
// biasreg stores bias * log2(e) (softmax runs in exp2 domain); masked = -60000.
__global__ void prep_kernel(const float* __restrict__ Wq, const float* __restrict__ bqkv,
                            const float* __restrict__ Wo, const float* __restrict__ Brel,
                            f16* __restrict__ wqd, f16* __restrict__ wod,
                            float* __restrict__ bqd, f16* __restrict__ biasreg) {
  int tid = blockIdx.x * blockDim.x + threadIdx.x;
  int nthr = gridDim.x * blockDim.x;
  for (int i = tid; i < 3 * 192 * 192; i += nthr) {
    int c = i % 192, n = (i / 192) % 192, kk = i / (192 * 192);
    wqd[i] = (f16)Wq[(size_t)(n * 3 + kk) * 192 + c];
  }
  for (int i = tid; i < 192 * 192; i += nthr) wod[i] = (f16)Wo[i];
  for (int i = tid; i < 3 * 192; i += nthr) {
    int n = i % 192, kk = i / 192;
    bqd[i] = bqkv[n * 3 + kk];
  }
  for (int idx = tid; idx < 4 * 4 * 4 * 64 * 4; idx += nthr) {
    int m = idx & 3, lane = (idx >> 2) & 63, jt = (idx >> 8) & 3,
        itt = (idx >> 10) & 3, t = idx >> 12;
    int i = itt * 16 + (lane & 15);
    int j = jt * 16 + 4 * (lane >> 4) + m;
    float v = -60000.0f;
    if (i < 49 && j < 49) {
      bool msk = false;
      if (t & 2) msk |= ((i / 7 >= 4) != (j / 7 >= 4));
      if (t & 1) msk |= ((i % 7 >= 4) != (j % 7 >= 4));
      if (!msk) {
        // numpy PyArray_Arange + DOUBLE_fill: delta = fl(1+1/7) - 1
        volatile double one = 1.0;
        volatile double step = 1.0 / 7.0;
        volatile double b1 = one + step;
        volatile double delta = b1 - one;
        volatile double mj = (double)j * delta;
        volatile double sj = 1.0 + mj;
        volatile double mi = (double)i * delta;
        volatile double si = 1.0 + mi;
        double d = (double)sj - (double)si;
        int xd = (int)d;
        int yd = (j % 7) - (i % 7);
        int xm = ((xd % 13) + 13) % 13;
        int ym = ((yd % 13) + 13) % 13;
        v = Brel[xm * 13 + ym] * 1.4426950408889634f;   // log2(e) fold
      }
    }
    biasreg[idx] = (f16)v;
  }
}

// ---------------- fused shifted-window MSA (r17 + O-buffer + 2-pass) ----------------
// Block = 768 threads = 12 waves; waves 0-5 = heads of window (b even), waves
// 6-11 = heads of window (b odd), same (wh,ww). Two stateless sequential passes
// per block (pairs 2g, 2g+1) halve per-CU block cold-starts. O goes to a
// DEDICATED LDS buffer (not xsm reuse) -> only 2 barriers per pass. Early-done
// waves start next pass's staging while stragglers finish phase 3 (disjoint
// LDS). Burst NT staging; merged QKV; exp2 softmax; direct NT Z stores.
__launch_bounds__(768, 3)
__global__ void swin_kernel(const float* __restrict__ x,
                            const float* __restrict__ bqd,
                            const float* __restrict__ bout,
                            const f16* __restrict__ wqd,
                            const f16* __restrict__ wod,
                            const f16* __restrict__ biasreg,
                            float* __restrict__ out) {
  __shared__ __align__(16) unsigned char xsm[2 * 64 * 384];   // x tiles (swizzled)
  __shared__ __align__(16) unsigned char osm[2 * 64 * 384];   // O tiles (swizzled)

  const int tid = threadIdx.x;
  const int bid = blockIdx.x;
  const int g  = bid >> 6;            // group: pairs 2g, 2g+1 (batches 4g..4g+3)
  const int wh = (bid >> 3) & 7;
  const int ww = bid & 7;
  const int lane = tid & 63;
  const int wv = tid >> 6;            // 0..11
  const int t  = (wv >= 6) ? 1 : 0;   // window within pair
  const int hd = wv - 6 * t;          // head
  const int lr = lane & 15;
  const int lg = lane >> 4;

#define XP(tt, row, cb) ((void*)(xsm + (tt) * 24576 + (row) * 384 + ((cb) ^ (((row) & 7) << 4))))
#define OP(tt, row, cb) ((void*)(osm + (tt) * 24576 + (row) * 384 + ((cb) ^ (((row) & 7) << 4))))

  // ---- bias table (register layout; fixed (wh,ww) for whole block) ----
  f16x4 br[4][4];
  {
    int msk = ((wh == 7) ? 2 : 0) | ((ww == 7) ? 1 : 0);
    #pragma unroll
    for (int itt = 0; itt < 4; ++itt)
      #pragma unroll
      for (int jt = 0; jt < 4; ++jt)
        br[itt][jt] = *(const f16x4*)(biasreg + ((((msk * 4 + itt) * 4 + jt) * 64 + lane) * 4));
  }

  for (int w = 0; w < 2; ++w) {
    const int p = g * 2 + w;          // batch pair: b = 2p+t

    // ---- stage both x windows (roll -4) into swizzled LDS, f16, burst NT ----
    {
#define SLOAD(K, DST)                                                        \
      { int idx = tid + (K) * 768;                                           \
        if ((K) < 6 || idx < 4704) {                                         \
          int tw = idx / 2352, r = idx % 2352;                               \
          int tok = r / 48, c4 = r % 48;                                     \
          const float* xb = x + (size_t)(2 * p + tw) * (3136 * 192);         \
          int m1 = tok / 7, m2 = tok % 7;                                    \
          int y  = wh * 7 + m1 + 4; if (y  >= 56) y  -= 56;                  \
          int xx = ww * 7 + m2 + 4; if (xx >= 56) xx -= 56;                  \
          DST = __builtin_nontemporal_load(                                  \
              (const f32x4*)(xb + ((y * 56 + xx) * 192 + c4 * 4)));          \
        } }
#define SSTORE(K, SRC)                                                       \
      { int idx = tid + (K) * 768;                                           \
        if ((K) < 6 || idx < 4704) {                                         \
          int tw = idx / 2352, r = idx % 2352;                               \
          int tok = r / 48, c4 = r % 48;                                     \
          f16x4 h = { (f16)SRC[0], (f16)SRC[1], (f16)SRC[2], (f16)SRC[3] };  \
          *(f16x4*)XP(tw, tok, c4 * 8) = h;                                  \
        } }
      f32x4 s0, s1, s2, s3, s4, s5, s6;
      SLOAD(0, s0) SLOAD(1, s1) SLOAD(2, s2) SLOAD(3, s3)
      SLOAD(4, s4) SLOAD(5, s5) SLOAD(6, s6)
      SSTORE(0, s0) SSTORE(1, s1) SSTORE(2, s2) SSTORE(3, s3)
      SSTORE(4, s4) SSTORE(5, s5) SSTORE(6, s6)
#undef SLOAD
#undef SSTORE
      if (w == 0) {
        for (int idx = tid; idx < 2 * 15 * 24; idx += 768) {  // zero pad rows once
          int tw = idx / (15 * 24), r = idx % (15 * 24);
          int tok = 49 + r / 24, c8 = r % 24;
          f16x8 z = {};
          *(f16x8*)XP(tw, tok, c8 * 16) = z;
        }
      }
    }
    __syncthreads();   // B1: x staged

    // ---- merged QKV: Qt,Kt = W @ x^T (C[n][i]) and V = x @ Wv^T (C[j][e]) ----
    f16x4 qtf[2][4], ktf[2][4], vf[4][2];
    {
      f32x4 qacc[2][4], kacc[2][4], vacc[4][2];
      #pragma unroll
      for (int nt = 0; nt < 2; ++nt)
        #pragma unroll
        for (int it = 0; it < 4; ++it) {
          qacc[nt][it] = (f32x4){0.f, 0.f, 0.f, 0.f};
          kacc[nt][it] = (f32x4){0.f, 0.f, 0.f, 0.f};
          vacc[it][nt] = (f32x4){0.f, 0.f, 0.f, 0.f};
        }
      #pragma unroll
      for (int ks = 0; ks < 6; ++ks) {
        f16x8 a[4];
        #pragma unroll
        for (int it = 0; it < 4; ++it)
          a[it] = *(const f16x8*)XP(t, it * 16 + lr, ks * 64 + lg * 16);
        #pragma unroll
        for (int nt = 0; nt < 2; ++nt) {
          const size_t roff = (size_t)(hd * 32 + nt * 16 + lr) * 192 + ks * 32 + lg * 8;
          f16x8 wqf = *(const f16x8*)(wqd + roff);                       // kk=0 plane
          f16x8 wkf = *(const f16x8*)(wqd + 192 * 192 + roff);           // kk=1 plane
          f16x8 wvf = *(const f16x8*)(wqd + 2 * 192 * 192 + roff);       // kk=2 plane
          #pragma unroll
          for (int it = 0; it < 4; ++it) {
            qacc[nt][it] = MFMA32(wqf, a[it], qacc[nt][it]);
            kacc[nt][it] = MFMA32(wkf, a[it], kacc[nt][it]);
            vacc[it][nt] = MFMA32(a[it], wvf, vacc[it][nt]);
          }
        }
      }
      // SCALE = 1/sqrt(32) * log2(e) (softmax in exp2 domain)
      const float SCALE = 0.25506953149031344f;
      #pragma unroll
      for (int nt = 0; nt < 2; ++nt) {
        float4 bq4 = *(const float4*)(bqd + hd * 32 + nt * 16 + 4 * lg);
        float4 bk4 = *(const float4*)(bqd + 192 + hd * 32 + nt * 16 + 4 * lg);
        float bv = bqd[2 * 192 + hd * 32 + nt * 16 + lr];
        #pragma unroll
        for (int it = 0; it < 4; ++it) {
          f16x4 q, k, v;
          q[0] = (f16)((qacc[nt][it][0] + bq4.x) * SCALE);
          q[1] = (f16)((qacc[nt][it][1] + bq4.y) * SCALE);
          q[2] = (f16)((qacc[nt][it][2] + bq4.z) * SCALE);
          q[3] = (f16)((qacc[nt][it][3] + bq4.w) * SCALE);
          k[0] = (f16)(kacc[nt][it][0] + bk4.x);
          k[1] = (f16)(kacc[nt][it][1] + bk4.y);
          k[2] = (f16)(kacc[nt][it][2] + bk4.z);
          k[3] = (f16)(kacc[nt][it][3] + bk4.w);
          #pragma unroll
          for (int m = 0; m < 4; ++m) v[m] = (f16)(vacc[it][nt][m] + bv);
          qtf[nt][it] = q; ktf[nt][it] = k; vf[it][nt] = v;
        }
      }
    }

    // ---- S^T = K @ Q^T ----
    f32x4 sacc[4][4];
    #pragma unroll
    for (int jt = 0; jt < 4; ++jt)
      #pragma unroll
      for (int it = 0; it < 4; ++it) {
        f32x4 c = (f32x4){0.f, 0.f, 0.f, 0.f};
        c = MFMA16(ktf[0][jt], qtf[0][it], c);
        sacc[jt][it] = MFMA16(ktf[1][jt], qtf[1][it], c);
      }

    // ---- softmax (exp2 domain, max-free) per query-col ----
    f16x4 paf[4][4];
    #pragma unroll
    for (int itt = 0; itt < 4; ++itt) {
      float sv[16];
      float sum = 0.f;
      #pragma unroll
      for (int jt = 0; jt < 4; ++jt)
        #pragma unroll
        for (int m = 0; m < 4; ++m) {
          float e = __builtin_amdgcn_exp2f(sacc[jt][itt][m] + (float)br[itt][jt][m]);
          sv[jt * 4 + m] = e;
          sum += e;
        }
      sum += __shfl_xor(sum, 16);
      sum += __shfl_xor(sum, 32);
      float rv = 1.0f / sum;
      #pragma unroll
      for (int jt = 0; jt < 4; ++jt) {
        f16x4 pk = { (f16)(sv[jt*4+0] * rv), (f16)(sv[jt*4+1] * rv),
                     (f16)(sv[jt*4+2] * rv), (f16)(sv[jt*4+3] * rv) };
        paf[jt][itt] = pk;
      }
    }

    // ---- O = P @ V ----
    f32x4 oacc[4][2];
    #pragma unroll
    for (int it = 0; it < 4; ++it)
      #pragma unroll
      for (int et = 0; et < 2; ++et) {
        f32x4 c = (f32x4){0.f, 0.f, 0.f, 0.f};
        #pragma unroll
        for (int jt = 0; jt < 4; ++jt)
          c = MFMA16(paf[jt][it], vf[jt][et], c);
        oacc[it][et] = c;
      }

    // ---- O -> dedicated LDS buffer: O[i][head*32+e], swizzled (no barrier needed:
    //      B1 guaranteed all waves are past last pass's osm reads) ----
    #pragma unroll
    for (int it = 0; it < 4; ++it)
      #pragma unroll
      for (int et = 0; et < 2; ++et)
        #pragma unroll
        for (int m = 0; m < 4; ++m) {
          int i = it * 16 + 4 * lg + m;
          *(f16*)OP(t, i, hd * 64 + et * 32 + lr * 2) = (f16)(oacc[it][et][m]);
        }
    __syncthreads();   // B2: O visible to all waves

    // ---- phase 3: Z = O @ Wo^T + bo; DIRECT NT stores (C[i][n], rolled +3) ----
    {
      f32x4 zacc[2][4];
      #pragma unroll
      for (int nt = 0; nt < 2; ++nt)
        #pragma unroll
        for (int it = 0; it < 4; ++it)
          zacc[nt][it] = (f32x4){0.f, 0.f, 0.f, 0.f};
      #pragma unroll
      for (int ks = 0; ks < 6; ++ks) {
        f16x8 a[4];
        #pragma unroll
        for (int it = 0; it < 4; ++it)
          a[it] = *(const f16x8*)OP(t, it * 16 + lr, ks * 64 + lg * 16);
        #pragma unroll
        for (int nt = 0; nt < 2; ++nt) {
          f16x8 bw = *(const f16x8*)(wod + (size_t)(hd * 32 + nt * 16 + lr) * 192 + ks * 32 + lg * 8);
          #pragma unroll
          for (int it = 0; it < 4; ++it)
            zacc[nt][it] = MFMA32(a[it], bw, zacc[nt][it]);
        }
      }
      float bo0 = bout[hd * 32 + lr];
      float bo1 = bout[hd * 32 + 16 + lr];
      float* outb = out + (size_t)(2 * p + t) * (3136 * 192);
      #pragma unroll
      for (int it = 0; it < 4; ++it) {
        #pragma unroll
        for (int m = 0; m < 4; ++m) {
          int i = it * 16 + lg * 4 + m;
          if (i < 49) {
            int m1 = i / 7, m2 = i % 7;
            int y  = wh * 7 + m1 + 3; if (y  >= 56) y  -= 56;
            int xx = ww * 7 + m2 + 3; if (xx >= 56) xx -= 56;
            float* rowp = outb + (size_t)(y * 56 + xx) * 192 + hd * 32 + lr;
            // nt=0 / nt=1 adjacent: together they fully dirty this head's 128B line
            __builtin_nontemporal_store(zacc[0][it][m] + bo0, rowp);
            __builtin_nontemporal_store(zacc[1][it][m] + bo1, rowp + 16);
          }
        }
      }
    }
    // next pass's staging (xsm) is disjoint from osm reads; B1 of next pass
    // fences xsm overwrite against this pass's QKV reads (all waves past B2
    // here are past their xsm reads already).
  }
#undef XP
#undef OP
}

extern "C" void kernel_launch(void* const* d_in, const int* in_sizes, int n_in,
                              void* d_out, int out_size, void* d_ws, size_t ws_size,
                              hipStream_t stream) {
  const float* x    = (const float*)d_in[0];
  const float* Wq   = (const float*)d_in[1];
  const float* bq   = (const float*)d_in[2];
  const float* Wo   = (const float*)d_in[3];
  const float* bo   = (const float*)d_in[4];
  const float* Brel = (const float*)d_in[5];

  f16*   wqd     = (f16*)d_ws;                         // 3*192*192*2 = 221184 B
  f16*   wod     = (f16*)((char*)d_ws + 0x38000);      // 192*192*2   =  73728 B
  float* bqd     = (float*)((char*)d_ws + 0x4A000);    // 3*192*4     =   2304 B
  f16*   biasreg = (f16*)((char*)d_ws + 0x4B000);      // 4*4*4*64*4*2=  32768 B

  hipLaunchKernelGGL(prep_kernel, dim3(256), dim3(256), 0, stream,
                     Wq, bq, Wo, Brel, wqd, wod, bqd, biasreg);
  hipLaunchKernelGGL(swin_kernel, dim3(8 * 8 * 8), dim3(768), 0, stream,
                     x, bqd, bo, wqd, wod, biasreg, (float*)d_out);
}

// Round 19
// 151.442 us; speedup vs baseline: 3.4916x; 3.4916x over previous
//
#include <hip/hip_runtime.h>

typedef _Float16 f16;
typedef _Float16 f16x4 __attribute__((ext_vector_type(4)));
typedef _Float16 f16x8 __attribute__((ext_vector_type(8)));
typedef float f32x4 __attribute__((ext_vector_type(4)));

#define MFMA32(A, B, C) __builtin_amdgcn_mfma_f32_16x16x32_f16((A), (B), (C), 0, 0, 0)
#if __has_builtin(__builtin_amdgcn_mfma_f32_16x16x16_f16)
#define MFMA16(A, B, C) __builtin_amdgcn_mfma_f32_16x16x16_f16((A), (B), (C), 0, 0, 0)
#else
#define MFMA16(A, B, C) __builtin_amdgcn_mfma_f32_16x16x16f16((A), (B), (C), 0, 0, 0)
#endif

// ---------------- prep: deinterleave weights to f16, bias tables ----------------
// biasreg stores bias * log2(e) (softmax runs in exp2 domain); masked = -60000.
__global__ void prep_kernel(const float* __restrict__ Wq, const float* __restrict__ bqkv,
                            const float* __restrict__ Wo, const float* __restrict__ Brel,
                            f16* __restrict__ wqd, f16* __restrict__ wod,
                            float* __restrict__ bqd, f16* __restrict__ biasreg) {
  int tid = blockIdx.x * blockDim.x + threadIdx.x;
  int nthr = gridDim.x * blockDim.x;
  for (int i = tid; i < 3 * 192 * 192; i += nthr) {
    int c = i % 192, n = (i / 192) % 192, kk = i / (192 * 192);
    wqd[i] = (f16)Wq[(size_t)(n * 3 + kk) * 192 + c];
  }
  for (int i = tid; i < 192 * 192; i += nthr) wod[i] = (f16)Wo[i];
  for (int i = tid; i < 3 * 192; i += nthr) {
    int n = i % 192, kk = i / 192;
    bqd[i] = bqkv[n * 3 + kk];
  }
  for (int idx = tid; idx < 4 * 4 * 4 * 64 * 4; idx += nthr) {
    int m = idx & 3, lane = (idx >> 2) & 63, jt = (idx >> 8) & 3,
        itt = (idx >> 10) & 3, t = idx >> 12;
    int i = itt * 16 + (lane & 15);
    int j = jt * 16 + 4 * (lane >> 4) + m;
    float v = -60000.0f;
    if (i < 49 && j < 49) {
      bool msk = false;
      if (t & 2) msk |= ((i / 7 >= 4) != (j / 7 >= 4));
      if (t & 1) msk |= ((i % 7 >= 4) != (j % 7 >= 4));
      if (!msk) {
        // numpy PyArray_Arange + DOUBLE_fill: delta = fl(1+1/7) - 1
        volatile double one = 1.0;
        volatile double step = 1.0 / 7.0;
        volatile double b1 = one + step;
        volatile double delta = b1 - one;
        volatile double mj = (double)j * delta;
        volatile double sj = 1.0 + mj;
        volatile double mi = (double)i * delta;
        volatile double si = 1.0 + mi;
        double d = (double)sj - (double)si;
        int xd = (int)d;
        int yd = (j % 7) - (i % 7);
        int xm = ((xd % 13) + 13) % 13;
        int ym = ((yd % 13) + 13) % 13;
        v = Brel[xm * 13 + ym] * 1.4426950408889634f;   // log2(e) fold
      }
    }
    biasreg[idx] = (f16)v;
  }
}

// ---------------- fused shifted-window MSA (r17 + dedicated O buffer + setprio) ----------------
// Block = 768 threads = 12 waves; waves 0-5 = heads of window (b=2p), waves
// 6-11 = heads of window (b=2p+1), same (wh,ww). Single pass (NO work loop —
// looped-work variants consistently balloon scratch traffic). O goes to a
// dedicated LDS buffer -> 2 barriers total. Burst NT staging; merged QKV;
// exp2 softmax; direct NT Z stores; s_setprio around MFMA clusters (T5).
__launch_bounds__(768, 3)
__global__ void swin_kernel(const float* __restrict__ x,
                            const float* __restrict__ bqd,
                            const float* __restrict__ bout,
                            const f16* __restrict__ wqd,
                            const f16* __restrict__ wod,
                            const f16* __restrict__ biasreg,
                            float* __restrict__ out) {
  __shared__ __align__(16) unsigned char xsm[2 * 64 * 384];   // x tiles (swizzled)
  __shared__ __align__(16) unsigned char osm[2 * 64 * 384];   // O tiles (swizzled)

  const int tid = threadIdx.x;
  const int bid = blockIdx.x;
  const int p  = bid >> 6;            // batch pair: b = 2p+t
  const int wh = (bid >> 3) & 7;
  const int ww = bid & 7;
  const int lane = tid & 63;
  const int wv = tid >> 6;            // 0..11
  const int t  = (wv >= 6) ? 1 : 0;   // window within pair
  const int hd = wv - 6 * t;          // head
  const int lr = lane & 15;
  const int lg = lane >> 4;

#define XP(tt, row, cb) ((void*)(xsm + (tt) * 24576 + (row) * 384 + ((cb) ^ (((row) & 7) << 4))))
#define OP(tt, row, cb) ((void*)(osm + (tt) * 24576 + (row) * 384 + ((cb) ^ (((row) & 7) << 4))))

  // ---- phase 0: burst-stage both x windows (roll -4) into swizzled LDS, f16 ----
  {
#define SLOAD(K, DST)                                                        \
    { int idx = tid + (K) * 768;                                             \
      if ((K) < 6 || idx < 4704) {                                           \
        int tw = idx / 2352, r = idx % 2352;                                 \
        int tok = r / 48, c4 = r % 48;                                       \
        const float* xb = x + (size_t)(2 * p + tw) * (3136 * 192);           \
        int m1 = tok / 7, m2 = tok % 7;                                      \
        int y  = wh * 7 + m1 + 4; if (y  >= 56) y  -= 56;                    \
        int xx = ww * 7 + m2 + 4; if (xx >= 56) xx -= 56;                    \
        DST = __builtin_nontemporal_load(                                    \
            (const f32x4*)(xb + ((y * 56 + xx) * 192 + c4 * 4)));            \
      } }
#define SSTORE(K, SRC)                                                       \
    { int idx = tid + (K) * 768;                                             \
      if ((K) < 6 || idx < 4704) {                                           \
        int tw = idx / 2352, r = idx % 2352;                                 \
        int tok = r / 48, c4 = r % 48;                                       \
        f16x4 h = { (f16)SRC[0], (f16)SRC[1], (f16)SRC[2], (f16)SRC[3] };    \
        *(f16x4*)XP(tw, tok, c4 * 8) = h;                                    \
      } }
    f32x4 s0, s1, s2, s3, s4, s5, s6;
    SLOAD(0, s0) SLOAD(1, s1) SLOAD(2, s2) SLOAD(3, s3)
    SLOAD(4, s4) SLOAD(5, s5) SLOAD(6, s6)
    SSTORE(0, s0) SSTORE(1, s1) SSTORE(2, s2) SSTORE(3, s3)
    SSTORE(4, s4) SSTORE(5, s5) SSTORE(6, s6)
#undef SLOAD
#undef SSTORE
    for (int idx = tid; idx < 2 * 15 * 24; idx += 768) {   // zero rows 49..63
      int tw = idx / (15 * 24), r = idx % (15 * 24);
      int tok = 49 + r / 24, c8 = r % 24;
      f16x8 z = {};
      *(f16x8*)XP(tw, tok, c8 * 16) = z;
    }
  }
  __syncthreads();   // B1

  // ---- bias table (register layout; shared by both windows — same wh,ww) ----
  f16x4 br[4][4];
  {
    int msk = ((wh == 7) ? 2 : 0) | ((ww == 7) ? 1 : 0);
    #pragma unroll
    for (int itt = 0; itt < 4; ++itt)
      #pragma unroll
      for (int jt = 0; jt < 4; ++jt)
        br[itt][jt] = *(const f16x4*)(biasreg + ((((msk * 4 + itt) * 4 + jt) * 64 + lane) * 4));
  }

  // ---- phase 1 (merged): Qt,Kt = W @ x^T (C[n][i]) and V = x @ Wv^T (C[j][e]) ----
  f16x4 qtf[2][4], ktf[2][4], vf[4][2];
  {
    f32x4 qacc[2][4], kacc[2][4], vacc[4][2];
    #pragma unroll
    for (int nt = 0; nt < 2; ++nt)
      #pragma unroll
      for (int it = 0; it < 4; ++it) {
        qacc[nt][it] = (f32x4){0.f, 0.f, 0.f, 0.f};
        kacc[nt][it] = (f32x4){0.f, 0.f, 0.f, 0.f};
        vacc[it][nt] = (f32x4){0.f, 0.f, 0.f, 0.f};
      }
    __builtin_amdgcn_s_setprio(1);
    #pragma unroll
    for (int ks = 0; ks < 6; ++ks) {
      f16x8 a[4];
      #pragma unroll
      for (int it = 0; it < 4; ++it)
        a[it] = *(const f16x8*)XP(t, it * 16 + lr, ks * 64 + lg * 16);
      #pragma unroll
      for (int nt = 0; nt < 2; ++nt) {
        const size_t roff = (size_t)(hd * 32 + nt * 16 + lr) * 192 + ks * 32 + lg * 8;
        f16x8 wqf = *(const f16x8*)(wqd + roff);                       // kk=0 plane
        f16x8 wkf = *(const f16x8*)(wqd + 192 * 192 + roff);           // kk=1 plane
        f16x8 wvf = *(const f16x8*)(wqd + 2 * 192 * 192 + roff);       // kk=2 plane
        #pragma unroll
        for (int it = 0; it < 4; ++it) {
          qacc[nt][it] = MFMA32(wqf, a[it], qacc[nt][it]);
          kacc[nt][it] = MFMA32(wkf, a[it], kacc[nt][it]);
          vacc[it][nt] = MFMA32(a[it], wvf, vacc[it][nt]);
        }
      }
    }
    __builtin_amdgcn_s_setprio(0);
    // SCALE = 1/sqrt(32) * log2(e), folded into Q (softmax runs in exp2 domain)
    const float SCALE = 0.25506953149031344f;
    #pragma unroll
    for (int nt = 0; nt < 2; ++nt) {
      float4 bq4 = *(const float4*)(bqd + hd * 32 + nt * 16 + 4 * lg);
      float4 bk4 = *(const float4*)(bqd + 192 + hd * 32 + nt * 16 + 4 * lg);
      float bv = bqd[2 * 192 + hd * 32 + nt * 16 + lr];
      #pragma unroll
      for (int it = 0; it < 4; ++it) {
        f16x4 q, k, v;
        q[0] = (f16)((qacc[nt][it][0] + bq4.x) * SCALE);
        q[1] = (f16)((qacc[nt][it][1] + bq4.y) * SCALE);
        q[2] = (f16)((qacc[nt][it][2] + bq4.z) * SCALE);
        q[3] = (f16)((qacc[nt][it][3] + bq4.w) * SCALE);
        k[0] = (f16)(kacc[nt][it][0] + bk4.x);
        k[1] = (f16)(kacc[nt][it][1] + bk4.y);
        k[2] = (f16)(kacc[nt][it][2] + bk4.z);
        k[3] = (f16)(kacc[nt][it][3] + bk4.w);
        #pragma unroll
        for (int m = 0; m < 4; ++m) v[m] = (f16)(vacc[it][nt][m] + bv);
        qtf[nt][it] = q; ktf[nt][it] = k; vf[it][nt] = v;
      }
    }
  }

  // ---- phase 2a: S^T = K @ Q^T ----
  f32x4 sacc[4][4];
  __builtin_amdgcn_s_setprio(1);
  #pragma unroll
  for (int jt = 0; jt < 4; ++jt)
    #pragma unroll
    for (int it = 0; it < 4; ++it) {
      f32x4 c = (f32x4){0.f, 0.f, 0.f, 0.f};
      c = MFMA16(ktf[0][jt], qtf[0][it], c);
      sacc[jt][it] = MFMA16(ktf[1][jt], qtf[1][it], c);
    }
  __builtin_amdgcn_s_setprio(0);

  // ---- softmax (exp2 domain) per query-col; masked = exp2(-6e4)=0; max-free ----
  f16x4 paf[4][4];
  #pragma unroll
  for (int itt = 0; itt < 4; ++itt) {
    float sv[16];
    float sum = 0.f;
    #pragma unroll
    for (int jt = 0; jt < 4; ++jt)
      #pragma unroll
      for (int m = 0; m < 4; ++m) {
        float e = __builtin_amdgcn_exp2f(sacc[jt][itt][m] + (float)br[itt][jt][m]);
        sv[jt * 4 + m] = e;
        sum += e;
      }
    sum += __shfl_xor(sum, 16);
    sum += __shfl_xor(sum, 32);
    float rv = 1.0f / sum;
    #pragma unroll
    for (int jt = 0; jt < 4; ++jt) {
      f16x4 pk = { (f16)(sv[jt*4+0] * rv), (f16)(sv[jt*4+1] * rv),
                   (f16)(sv[jt*4+2] * rv), (f16)(sv[jt*4+3] * rv) };
      paf[jt][itt] = pk;
    }
  }

  // ---- phase 2b: O = P @ V ----
  f32x4 oacc[4][2];
  __builtin_amdgcn_s_setprio(1);
  #pragma unroll
  for (int it = 0; it < 4; ++it)
    #pragma unroll
    for (int et = 0; et < 2; ++et) {
      f32x4 c = (f32x4){0.f, 0.f, 0.f, 0.f};
      #pragma unroll
      for (int jt = 0; jt < 4; ++jt)
        c = MFMA16(paf[jt][it], vf[jt][et], c);
      oacc[it][et] = c;
    }
  __builtin_amdgcn_s_setprio(0);

  // ---- O -> dedicated LDS buffer (no barrier needed before write) ----
  #pragma unroll
  for (int it = 0; it < 4; ++it)
    #pragma unroll
    for (int et = 0; et < 2; ++et)
      #pragma unroll
      for (int m = 0; m < 4; ++m) {
        int i = it * 16 + 4 * lg + m;
        *(f16*)OP(t, i, hd * 64 + et * 32 + lr * 2) = (f16)(oacc[it][et][m]);
      }
  __syncthreads();   // B2: O visible to all waves

  // ---- phase 3: Z = O @ Wo^T + bo; DIRECT NT stores (C[i][n], rolled +3) ----
  {
    f32x4 zacc[2][4];
    #pragma unroll
    for (int nt = 0; nt < 2; ++nt)
      #pragma unroll
      for (int it = 0; it < 4; ++it)
        zacc[nt][it] = (f32x4){0.f, 0.f, 0.f, 0.f};
    __builtin_amdgcn_s_setprio(1);
    #pragma unroll
    for (int ks = 0; ks < 6; ++ks) {
      f16x8 a[4];
      #pragma unroll
      for (int it = 0; it < 4; ++it)
        a[it] = *(const f16x8*)OP(t, it * 16 + lr, ks * 64 + lg * 16);
      #pragma unroll
      for (int nt = 0; nt < 2; ++nt) {
        f16x8 bw = *(const f16x8*)(wod + (size_t)(hd * 32 + nt * 16 + lr) * 192 + ks * 32 + lg * 8);
        #pragma unroll
        for (int it = 0; it < 4; ++it)
          zacc[nt][it] = MFMA32(a[it], bw, zacc[nt][it]);
      }
    }
    __builtin_amdgcn_s_setprio(0);
    float bo0 = bout[hd * 32 + lr];
    float bo1 = bout[hd * 32 + 16 + lr];
    float* outb = out + (size_t)(2 * p + t) * (3136 * 192);
    #pragma unroll
    for (int it = 0; it < 4; ++it) {
      #pragma unroll
      for (int m = 0; m < 4; ++m) {
        int i = it * 16 + lg * 4 + m;
        if (i < 49) {
          int m1 = i / 7, m2 = i % 7;
          int y  = wh * 7 + m1 + 3; if (y  >= 56) y  -= 56;
          int xx = ww * 7 + m2 + 3; if (xx >= 56) xx -= 56;
          float* rowp = outb + (size_t)(y * 56 + xx) * 192 + hd * 32 + lr;
          // nt=0 / nt=1 adjacent: together they fully dirty this head's 128B line
          __builtin_nontemporal_store(zacc[0][it][m] + bo0, rowp);
          __builtin_nontemporal_store(zacc[1][it][m] + bo1, rowp + 16);
        }
      }
    }
  }
#undef XP
#undef OP
}

extern "C" void kernel_launch(void* const* d_in, const int* in_sizes, int n_in,
                              void* d_out, int out_size, void* d_ws, size_t ws_size,
                              hipStream_t stream) {
  const float* x    = (const float*)d_in[0];
  const float* Wq   = (const float*)d_in[1];
  const float* bq   = (const float*)d_in[2];
  const float* Wo   = (const float*)d_in[3];
  const float* bo   = (const float*)d_in[4];
  const float* Brel = (const float*)d_in[5];

  f16*   wqd     = (f16*)d_ws;                         // 3*192*192*2 = 221184 B
  f16*   wod     = (f16*)((char*)d_ws + 0x38000);      // 192*192*2   =  73728 B
  float* bqd     = (float*)((char*)d_ws + 0x4A000);    // 3*192*4     =   2304 B
  f16*   biasreg = (f16*)((char*)d_ws + 0x4B000);      // 4*4*4*64*4*2=  32768 B

  hipLaunchKernelGGL(prep_kernel, dim3(256), dim3(256), 0, stream,
                     Wq, bq, Wo, Brel, wqd, wod, bqd, biasreg);
  hipLaunchKernelGGL(swin_kernel, dim3(16 * 8 * 8), dim3(768), 0, stream,
                     x, bqd, bo, wqd, wod, biasreg, (float*)d_out);
}

// Round 20
// 126.610 us; speedup vs baseline: 4.1764x; 1.1961x over previous
//
#include <hip/hip_runtime.h>

typedef _Float16 f16;
typedef _Float16 f16x4 __attribute__((ext_vector_type(4)));
typedef _Float16 f16x8 __attribute__((ext_vector_type(8)));
typedef float f32x4 __attribute__((ext_vector_type(4)));

#define MFMA32(A, B, C) __builtin_amdgcn_mfma_f32_16x16x32_f16((A), (B), (C), 0, 0, 0)
#if __has_builtin(__builtin_amdgcn_mfma_f32_16x16x16_f16)
#define MFMA16(A, B, C) __builtin_amdgcn_mfma_f32_16x16x16_f16((A), (B), (C), 0, 0, 0)
#else
#define MFMA16(A, B, C) __builtin_amdgcn_mfma_f32_16x16x16f16((A), (B), (C), 0, 0, 0)
#endif

// ---------------- prep: deinterleave weights to f16, bias tables ----------------
// biasreg stores bias * log2(e) (softmax runs in exp2 domain); masked = -60000.
__global__ void prep_kernel(const float* __restrict__ Wq, const float* __restrict__ bqkv,
                            const float* __restrict__ Wo, const float* __restrict__ Brel,
                            f16* __restrict__ wqd, f16* __restrict__ wod,
                            float* __restrict__ bqd, f16* __restrict__ biasreg) {
  int tid = blockIdx.x * blockDim.x + threadIdx.x;
  int nthr = gridDim.x * blockDim.x;
  for (int i = tid; i < 3 * 192 * 192; i += nthr) {
    int c = i % 192, n = (i / 192) % 192, kk = i / (192 * 192);
    wqd[i] = (f16)Wq[(size_t)(n * 3 + kk) * 192 + c];
  }
  for (int i = tid; i < 192 * 192; i += nthr) wod[i] = (f16)Wo[i];
  for (int i = tid; i < 3 * 192; i += nthr) {
    int n = i % 192, kk = i / 192;
    bqd[i] = bqkv[n * 3 + kk];
  }
  for (int idx = tid; idx < 4 * 4 * 4 * 64 * 4; idx += nthr) {
    int m = idx & 3, lane = (idx >> 2) & 63, jt = (idx >> 8) & 3,
        itt = (idx >> 10) & 3, t = idx >> 12;
    int i = itt * 16 + (lane & 15);
    int j = jt * 16 + 4 * (lane >> 4) + m;
    float v = -60000.0f;
    if (i < 49 && j < 49) {
      bool msk = false;
      if (t & 2) msk |= ((i / 7 >= 4) != (j / 7 >= 4));
      if (t & 1) msk |= ((i % 7 >= 4) != (j % 7 >= 4));
      if (!msk) {
        // numpy PyArray_Arange + DOUBLE_fill: delta = fl(1+1/7) - 1
        volatile double one = 1.0;
        volatile double step = 1.0 / 7.0;
        volatile double b1 = one + step;
        volatile double delta = b1 - one;
        volatile double mj = (double)j * delta;
        volatile double sj = 1.0 + mj;
        volatile double mi = (double)i * delta;
        volatile double si = 1.0 + mi;
        double d = (double)sj - (double)si;
        int xd = (int)d;
        int yd = (j % 7) - (i % 7);
        int xm = ((xd % 13) + 13) % 13;
        int ym = ((yd % 13) + 13) % 13;
        v = Brel[xm * 13 + ym] * 1.4426950408889634f;   // log2(e) fold
      }
    }
    biasreg[idx] = (f16)v;
  }
}

// ---------------- fused shifted-window MSA (r17 optimum, reverted) ----------------
// Block = 768 threads = 12 waves; waves 0-5 = heads of window (b=2p), waves
// 6-11 = heads of window (b=2p+1), same (wh,ww). Single pass, single item (all
// multi-item/looped variants balloon scratch traffic). Single QKV pass: each x
// fragment feeds 12 independent MFMA chains (q,k,v) per ks. Softmax in exp2
// domain (log2e folded into Q scale + bias table). Burst NT staging (7 loads in
// flight); xsm reused for O (3 barriers); Z stored directly from accumulators
// as full 128B lines (NT, no RFO). No setprio (hurts lockstep schedules, m190).
__launch_bounds__(768, 3)
__global__ void swin_kernel(const float* __restrict__ x,
                            const float* __restrict__ bqd,
                            const float* __restrict__ bout,
                            const f16* __restrict__ wqd,
                            const f16* __restrict__ wod,
                            const f16* __restrict__ biasreg,
                            float* __restrict__ out) {
  __shared__ __align__(16) unsigned char xsm[2 * 64 * 384];  // per window: [row][192 f16], swizzled

  const int tid = threadIdx.x;
  const int bid = blockIdx.x;
  const int p  = bid >> 6;            // batch pair: b = 2p+t
  const int wh = (bid >> 3) & 7;
  const int ww = bid & 7;
  const int lane = tid & 63;
  const int wv = tid >> 6;            // 0..11
  const int t  = (wv >= 6) ? 1 : 0;   // window within pair
  const int hd = wv - 6 * t;          // head
  const int lr = lane & 15;
  const int lg = lane >> 4;

#define XP(tt, row, cb) ((void*)(xsm + (tt) * 24576 + (row) * 384 + ((cb) ^ (((row) & 7) << 4))))

  // ---- phase 0: burst-stage both x windows (roll -4) into swizzled LDS, f16 ----
  {
#define SLOAD(K, DST)                                                        \
    { int idx = tid + (K) * 768;                                             \
      if ((K) < 6 || idx < 4704) {                                           \
        int tw = idx / 2352, r = idx % 2352;                                 \
        int tok = r / 48, c4 = r % 48;                                       \
        const float* xb = x + (size_t)(2 * p + tw) * (3136 * 192);           \
        int m1 = tok / 7, m2 = tok % 7;                                      \
        int y  = wh * 7 + m1 + 4; if (y  >= 56) y  -= 56;                    \
        int xx = ww * 7 + m2 + 4; if (xx >= 56) xx -= 56;                    \
        DST = __builtin_nontemporal_load(                                    \
            (const f32x4*)(xb + ((y * 56 + xx) * 192 + c4 * 4)));            \
      } }
#define SSTORE(K, SRC)                                                       \
    { int idx = tid + (K) * 768;                                             \
      if ((K) < 6 || idx < 4704) {                                           \
        int tw = idx / 2352, r = idx % 2352;                                 \
        int tok = r / 48, c4 = r % 48;                                       \
        f16x4 h = { (f16)SRC[0], (f16)SRC[1], (f16)SRC[2], (f16)SRC[3] };    \
        *(f16x4*)XP(tw, tok, c4 * 8) = h;                                    \
      } }
    f32x4 s0, s1, s2, s3, s4, s5, s6;
    SLOAD(0, s0) SLOAD(1, s1) SLOAD(2, s2) SLOAD(3, s3)
    SLOAD(4, s4) SLOAD(5, s5) SLOAD(6, s6)
    SSTORE(0, s0) SSTORE(1, s1) SSTORE(2, s2) SSTORE(3, s3)
    SSTORE(4, s4) SSTORE(5, s5) SSTORE(6, s6)
#undef SLOAD
#undef SSTORE
    for (int idx = tid; idx < 2 * 15 * 24; idx += 768) {   // zero rows 49..63
      int tw = idx / (15 * 24), r = idx % (15 * 24);
      int tok = 49 + r / 24, c8 = r % 24;
      f16x8 z = {};
      *(f16x8*)XP(tw, tok, c8 * 16) = z;
    }
  }
  __syncthreads();   // B1

  // ---- bias table (register layout; shared by both windows — same wh,ww) ----
  f16x4 br[4][4];
  {
    int msk = ((wh == 7) ? 2 : 0) | ((ww == 7) ? 1 : 0);
    #pragma unroll
    for (int itt = 0; itt < 4; ++itt)
      #pragma unroll
      for (int jt = 0; jt < 4; ++jt)
        br[itt][jt] = *(const f16x4*)(biasreg + ((((msk * 4 + itt) * 4 + jt) * 64 + lane) * 4));
  }

  // ---- phase 1 (merged): Qt,Kt = W @ x^T (C[n][i]) and V = x @ Wv^T (C[j][e]) ----
  f16x4 qtf[2][4], ktf[2][4], vf[4][2];
  {
    f32x4 qacc[2][4], kacc[2][4], vacc[4][2];
    #pragma unroll
    for (int nt = 0; nt < 2; ++nt)
      #pragma unroll
      for (int it = 0; it < 4; ++it) {
        qacc[nt][it] = (f32x4){0.f, 0.f, 0.f, 0.f};
        kacc[nt][it] = (f32x4){0.f, 0.f, 0.f, 0.f};
        vacc[it][nt] = (f32x4){0.f, 0.f, 0.f, 0.f};
      }
    #pragma unroll
    for (int ks = 0; ks < 6; ++ks) {
      f16x8 a[4];
      #pragma unroll
      for (int it = 0; it < 4; ++it)
        a[it] = *(const f16x8*)XP(t, it * 16 + lr, ks * 64 + lg * 16);
      #pragma unroll
      for (int nt = 0; nt < 2; ++nt) {
        const size_t roff = (size_t)(hd * 32 + nt * 16 + lr) * 192 + ks * 32 + lg * 8;
        f16x8 wqf = *(const f16x8*)(wqd + roff);                       // kk=0 plane
        f16x8 wkf = *(const f16x8*)(wqd + 192 * 192 + roff);           // kk=1 plane
        f16x8 wvf = *(const f16x8*)(wqd + 2 * 192 * 192 + roff);       // kk=2 plane
        #pragma unroll
        for (int it = 0; it < 4; ++it) {
          qacc[nt][it] = MFMA32(wqf, a[it], qacc[nt][it]);
          kacc[nt][it] = MFMA32(wkf, a[it], kacc[nt][it]);
          vacc[it][nt] = MFMA32(a[it], wvf, vacc[it][nt]);
        }
      }
    }
    // SCALE = 1/sqrt(32) * log2(e), folded into Q (softmax runs in exp2 domain)
    const float SCALE = 0.25506953149031344f;
    #pragma unroll
    for (int nt = 0; nt < 2; ++nt) {
      float4 bq4 = *(const float4*)(bqd + hd * 32 + nt * 16 + 4 * lg);
      float4 bk4 = *(const float4*)(bqd + 192 + hd * 32 + nt * 16 + 4 * lg);
      float bv = bqd[2 * 192 + hd * 32 + nt * 16 + lr];
      #pragma unroll
      for (int it = 0; it < 4; ++it) {
        f16x4 q, k, v;
        q[0] = (f16)((qacc[nt][it][0] + bq4.x) * SCALE);
        q[1] = (f16)((qacc[nt][it][1] + bq4.y) * SCALE);
        q[2] = (f16)((qacc[nt][it][2] + bq4.z) * SCALE);
        q[3] = (f16)((qacc[nt][it][3] + bq4.w) * SCALE);
        k[0] = (f16)(kacc[nt][it][0] + bk4.x);
        k[1] = (f16)(kacc[nt][it][1] + bk4.y);
        k[2] = (f16)(kacc[nt][it][2] + bk4.z);
        k[3] = (f16)(kacc[nt][it][3] + bk4.w);
        #pragma unroll
        for (int m = 0; m < 4; ++m) v[m] = (f16)(vacc[it][nt][m] + bv);
        qtf[nt][it] = q; ktf[nt][it] = k; vf[it][nt] = v;
      }
    }
  }

  // ---- phase 2a: S^T = K @ Q^T ----
  f32x4 sacc[4][4];
  #pragma unroll
  for (int jt = 0; jt < 4; ++jt)
    #pragma unroll
    for (int it = 0; it < 4; ++it) {
      f32x4 c = (f32x4){0.f, 0.f, 0.f, 0.f};
      c = MFMA16(ktf[0][jt], qtf[0][it], c);
      sacc[jt][it] = MFMA16(ktf[1][jt], qtf[1][it], c);
    }

  // ---- softmax (exp2 domain) per query-col; masked = exp2(-6e4)=0; max-free ----
  f16x4 paf[4][4];
  #pragma unroll
  for (int itt = 0; itt < 4; ++itt) {
    float sv[16];
    float sum = 0.f;
    #pragma unroll
    for (int jt = 0; jt < 4; ++jt)
      #pragma unroll
      for (int m = 0; m < 4; ++m) {
        float e = __builtin_amdgcn_exp2f(sacc[jt][itt][m] + (float)br[itt][jt][m]);
        sv[jt * 4 + m] = e;
        sum += e;
      }
    sum += __shfl_xor(sum, 16);
    sum += __shfl_xor(sum, 32);
    float rv = 1.0f / sum;
    #pragma unroll
    for (int jt = 0; jt < 4; ++jt) {
      f16x4 pk = { (f16)(sv[jt*4+0] * rv), (f16)(sv[jt*4+1] * rv),
                   (f16)(sv[jt*4+2] * rv), (f16)(sv[jt*4+3] * rv) };
      paf[jt][itt] = pk;
    }
  }

  // ---- phase 2b: O = P @ V ----
  f32x4 oacc[4][2];
  #pragma unroll
  for (int it = 0; it < 4; ++it)
    #pragma unroll
    for (int et = 0; et < 2; ++et) {
      f32x4 c = (f32x4){0.f, 0.f, 0.f, 0.f};
      #pragma unroll
      for (int jt = 0; jt < 4; ++jt)
        c = MFMA16(paf[jt][it], vf[jt][et], c);
      oacc[it][et] = c;
    }

  __syncthreads();   // B2: all x reads done everywhere

  // ---- O -> LDS (reuse xs region): O[i][head*32+e], swizzled ----
  #pragma unroll
  for (int it = 0; it < 4; ++it)
    #pragma unroll
    for (int et = 0; et < 2; ++et)
      #pragma unroll
      for (int m = 0; m < 4; ++m) {
        int i = it * 16 + 4 * lg + m;
        *(f16*)XP(t, i, hd * 64 + et * 32 + lr * 2) = (f16)(oacc[it][et][m]);
      }
  __syncthreads();   // B3

  // ---- phase 3: Z = O @ Wo^T + bo; DIRECT NT stores (C[i][n], rolled +3) ----
  {
    f32x4 zacc[2][4];
    #pragma unroll
    for (int nt = 0; nt < 2; ++nt)
      #pragma unroll
      for (int it = 0; it < 4; ++it)
        zacc[nt][it] = (f32x4){0.f, 0.f, 0.f, 0.f};
    #pragma unroll
    for (int ks = 0; ks < 6; ++ks) {
      f16x8 a[4];
      #pragma unroll
      for (int it = 0; it < 4; ++it)
        a[it] = *(const f16x8*)XP(t, it * 16 + lr, ks * 64 + lg * 16);
      #pragma unroll
      for (int nt = 0; nt < 2; ++nt) {
        f16x8 bw = *(const f16x8*)(wod + (size_t)(hd * 32 + nt * 16 + lr) * 192 + ks * 32 + lg * 8);
        #pragma unroll
        for (int it = 0; it < 4; ++it)
          zacc[nt][it] = MFMA32(a[it], bw, zacc[nt][it]);
      }
    }
    float bo0 = bout[hd * 32 + lr];
    float bo1 = bout[hd * 32 + 16 + lr];
    float* outb = out + (size_t)(2 * p + t) * (3136 * 192);
    #pragma unroll
    for (int it = 0; it < 4; ++it) {
      #pragma unroll
      for (int m = 0; m < 4; ++m) {
        int i = it * 16 + lg * 4 + m;
        if (i < 49) {
          int m1 = i / 7, m2 = i % 7;
          int y  = wh * 7 + m1 + 3; if (y  >= 56) y  -= 56;
          int xx = ww * 7 + m2 + 3; if (xx >= 56) xx -= 56;
          float* rowp = outb + (size_t)(y * 56 + xx) * 192 + hd * 32 + lr;
          // nt=0 / nt=1 adjacent: together they fully dirty this head's 128B line
          __builtin_nontemporal_store(zacc[0][it][m] + bo0, rowp);
          __builtin_nontemporal_store(zacc[1][it][m] + bo1, rowp + 16);
        }
      }
    }
  }
#undef XP
}

extern "C" void kernel_launch(void* const* d_in, const int* in_sizes, int n_in,
                              void* d_out, int out_size, void* d_ws, size_t ws_size,
                              hipStream_t stream) {
  const float* x    = (const float*)d_in[0];
  const float* Wq   = (const float*)d_in[1];
  const float* bq   = (const float*)d_in[2];
  const float* Wo   = (const float*)d_in[3];
  const float* bo   = (const float*)d_in[4];
  const float* Brel = (const float*)d_in[5];

  f16*   wqd     = (f16*)d_ws;                         // 3*192*192*2 = 221184 B
  f16*   wod     = (f16*)((char*)d_ws + 0x38000);      // 192*192*2   =  73728 B
  float* bqd     = (float*)((char*)d_ws + 0x4A000);    // 3*192*4     =   2304 B
  f16*   biasreg = (f16*)((char*)d_ws + 0x4B000);      // 4*4*4*64*4*2=  32768 B

  hipLaunchKernelGGL(prep_kernel, dim3(256), dim3(256), 0, stream,
                     Wq, bq, Wo, Brel, wqd, wod, bqd, biasreg);
  hipLaunchKernelGGL(swin_kernel, dim3(16 * 8 * 8), dim3(768), 0, stream,
                     x, bqd, bo, wqd, wod, biasreg, (float*)d_out);
}